// Round 6
// baseline (241.214 us; speedup 1.0000x reference)
//
#include <hip/hip_runtime.h>

// Problem constants (fixed by the reference)
constexpr int C_ = 2048;
constexpr int H_ = 16;
constexpr int W_ = 16;
constexpr int F_ = 64;
constexpr int P_ = 256;                 // samples per complex
constexpr int MAP4 = H_ * W_ * F_ / 4;  // 4096 float4 = 64 KB
constexpr int BLK = 1024;               // 16 waves per block
constexpr int NBLOCKS = 256;            // one persistent block per CU
constexpr int NC = C_ / NBLOCKS;        // 8 complexes per block
constexpr int ITERS = 4;                // phase-2 passes (64 samples each)

// Round-5 retry: same parity-stagger theory, but ALL barriers are plain
// __syncthreads() -- the previous attempt's hand-counted
// "s_waitcnt vmcnt(4)" + raw s_barrier could hang if the compiler's actual
// vmem queue differed from my hand count (container died twice; can't rule
// that out). This version has no inline asm at all.
//
// Theory recap: every structure so far pins at 2.4-2.7 TB/s with all on-CU
// resources idle. Shared trait: chip-wide phase lockstep (all blocks
// read-burst then write-burst together -> HBM alternates direction).
// Odd blocks here run one cold unpipelined complex first, permanently
// offsetting their phases ~half a period vs even blocks, so at any instant
// ~half the chip reads while half writes.
typedef __attribute__((address_space(3))) uint32_t lds_u32;
typedef const __attribute__((address_space(1))) uint32_t glb_u32;
using f32x4 = __attribute__((ext_vector_type(4))) float;

__global__ __launch_bounds__(BLK, 4) void ngf_fetch_kernel(
    const float* __restrict__ map_,
    const float* __restrict__ u_,
    const float* __restrict__ v_,
    float* __restrict__ out_) {
  __shared__ float4 smap[2][MAP4];   // 128 KB: double-buffered map tiles
  __shared__ float4 s_w[2][P_];      // (w00,w01,w10,w11) per sample, x2
  __shared__ int    s_ix[2][P_];     // (y0*W+x0)*(F/4) in float4 units, x2

  const int b = blockIdx.x;
  const int tid = threadIdx.x;
  const int f = tid & 15;        // float4 index along feature dim (0..15)
  const int sbase = tid >> 4;    // 0..63

  auto cidx = [&](int i) { return i * NBLOCKS + b; };

  auto stage = [&](int c, int buf) {
    const float4* __restrict__ g =
        (const float4*)(map_ + (size_t)c * (H_ * W_ * F_));
#pragma unroll
    for (int k = 0; k < MAP4 / BLK; ++k) {
      __builtin_amdgcn_global_load_lds((glb_u32*)(g + k * BLK + tid),
                                       (lds_u32*)(&smap[buf][k * BLK + tid]),
                                       16, 0, 0);
    }
  };

  auto coeffs = [&](int c, int buf) {
    if (tid < P_) {
      const float x = u_[(size_t)c * P_ + tid] * (float)(W_ - 1);
      const float y = v_[(size_t)c * P_ + tid] * (float)(H_ - 1);
      int x0 = (int)floorf(x);
      int y0 = (int)floorf(y);
      x0 = x0 < 0 ? 0 : (x0 > W_ - 2 ? W_ - 2 : x0);
      y0 = y0 < 0 ? 0 : (y0 > H_ - 2 ? H_ - 2 : y0);
      const float fx = x - (float)x0;
      const float fy = y - (float)y0;
      const float wx0 = 1.0f - fx;
      const float wy0 = 1.0f - fy;
      s_w[buf][tid] = make_float4(wx0 * wy0, fx * wy0, wx0 * fy, fx * fy);
      s_ix[buf][tid] = (y0 * W_ + x0) * (F_ / 4);
    }
  };

  auto compute_store = [&](int c, int buf) {
    float4 w[ITERS];
    int ix[ITERS];
#pragma unroll
    for (int it = 0; it < ITERS; ++it) {
      const int s = it * (BLK / 16) + sbase;
      w[it] = s_w[buf][s];
      ix[it] = s_ix[buf][s] + f;
    }
    float4* __restrict__ gout = (float4*)(out_ + (size_t)c * (P_ * F_));
#pragma unroll
    for (int it = 0; it < ITERS; ++it) {
      const int s = it * (BLK / 16) + sbase;
      const float4 g00 = smap[buf][ix[it]];
      const float4 g01 = smap[buf][ix[it] + (F_ / 4)];            // x0+1
      const float4 g10 = smap[buf][ix[it] + W_ * (F_ / 4)];       // y0+1
      const float4 g11 = smap[buf][ix[it] + (W_ + 1) * (F_ / 4)]; // y0+1,x0+1

      f32x4 r;
      r.x = g00.x * w[it].x + g01.x * w[it].y + g10.x * w[it].z + g11.x * w[it].w;
      r.y = g00.y * w[it].x + g01.y * w[it].y + g10.y * w[it].z + g11.y * w[it].w;
      r.z = g00.z * w[it].x + g01.z * w[it].y + g10.z * w[it].z + g11.z * w[it].w;
      r.w = g00.w * w[it].x + g01.w * w[it].y + g10.w * w[it].z + g11.w * w[it].w;

      __builtin_nontemporal_store(r, (f32x4*)(gout + s * (F_ / 4) + f));
    }
  };

  // ---- prologue: stage complex 0 ----
  int i = 0, cur = 0;
  stage(cidx(0), 0);
  coeffs(cidx(0), 0);
  __syncthreads();   // full drain: DMA(0) landed, coeffs(0) visible

  if (b & 1) {
    // Cold, unpipelined first complex: permanently phase-shifts this block
    // ~half a period vs even blocks -> chip-wide R/W streams interleave.
    compute_store(cidx(0), 0);
    __syncthreads();            // drain stores (part of the deliberate shift)
    stage(cidx(1), 1);
    coeffs(cidx(1), 1);
    __syncthreads();            // full drain: DMA(1) landed
    i = 1;
    cur = 1;
  }

  // ---- steady pipeline: DMA(i+1) in flight during compute/store(i) ----
  for (; i < NC; ++i) {
    const int nxt = cur ^ 1;
    if (i + 1 < NC) {
      stage(cidx(i + 1), nxt);   // fire-and-forget DMA into other buffer
      coeffs(cidx(i + 1), nxt);  // uv loads + coeff ds_writes
    }
    compute_store(cidx(i), cur); // overlaps with the in-flight DMA

    __syncthreads();             // full drain (safe): DMA+stores done,
                                 // coeffs visible, buffers swappable
    cur = nxt;
  }
}

extern "C" void kernel_launch(void* const* d_in, const int* in_sizes, int n_in,
                              void* d_out, int out_size, void* d_ws, size_t ws_size,
                              hipStream_t stream) {
  const float* map_ = (const float*)d_in[0];
  const float* u_   = (const float*)d_in[1];
  const float* v_   = (const float*)d_in[2];
  float* out_ = (float*)d_out;

  ngf_fetch_kernel<<<NBLOCKS, BLK, 0, stream>>>(map_, u_, v_, out_);
}

// Round 7
// 240.261 us; speedup vs baseline: 1.0040x; 1.0040x over previous
//
#include <hip/hip_runtime.h>

// Problem constants (fixed by the reference)
constexpr int C_ = 2048;
constexpr int H_ = 16;
constexpr int W_ = 16;
constexpr int F_ = 64;
constexpr int P_ = 256;                 // samples per complex
constexpr int MAP4 = H_ * W_ * F_ / 4;  // 4096 float4 = 64 KB
constexpr int BLK = 1024;               // 16 waves per block
constexpr int NBLOCKS = 256;            // one persistent block per CU
constexpr int NC = C_ / NBLOCKS;        // 8 complexes per block
constexpr int ITERS = 4;                // phase-2 passes (64 samples each)

// Round-6 lessons: (a) stagger flat -> chip-wide R/W mixing is NOT the
// limiter; (b) the harness's own fillBuffer hit 6.7 TB/s (83% peak) on this
// exact machine -> 2.4 TB/s is not a platform rate. Revised theory: every
// variant drains OUTPUT STORES at every phase barrier (__syncthreads ==
// s_waitcnt vmcnt(0)) -- ~2.5+us/phase of dead time where the CU's single
// block sits at the barrier. Stores feed nothing; only DMA(i+1) (vmem) and
// LDS reads (lgkm) need waiting. Fix = T4 counted vmcnt: the loop body has
// EXACTLY 8 vmem ops (4 global_load_lds then 4 nt stores, order pinned by
// sched_barrier(0)); "s_waitcnt vmcnt(4)" completes DMA + prior-phase stores
// while letting this phase's 4 stores fly across the barrier. All coeffs for
// all 8 complexes are precomputed into LDS in the prologue so no other vmem
// op can perturb the count. No divergent barriers -> no hang mode.
typedef __attribute__((address_space(3))) uint32_t lds_u32;
typedef const __attribute__((address_space(1))) uint32_t glb_u32;
using f32x4 = __attribute__((ext_vector_type(4))) float;

__global__ __launch_bounds__(BLK, 4) void ngf_fetch_kernel(
    const float* __restrict__ map_,
    const float* __restrict__ u_,
    const float* __restrict__ v_,
    float* __restrict__ out_) {
  __shared__ float4 smap[2][MAP4];     // 128 KB: double-buffered map tiles
  __shared__ float2 s_cf[NC * P_];     // 16 KB: (fx,fy) per sample, all 8 cplx
  __shared__ int    s_ix[NC * P_];     // 8 KB: (y0*W+x0)*(F/4), float4 units

  const int b = blockIdx.x;
  const int tid = threadIdx.x;
  const int f = tid & 15;        // float4 index along feature dim (0..15)
  const int sbase = tid >> 4;    // 0..63

  auto stage = [&](int c, int buf) {
    const float4* __restrict__ g =
        (const float4*)(map_ + (size_t)c * (H_ * W_ * F_));
#pragma unroll
    for (int k = 0; k < MAP4 / BLK; ++k) {
      __builtin_amdgcn_global_load_lds((glb_u32*)(g + k * BLK + tid),
                                       (lds_u32*)(&smap[buf][k * BLK + tid]),
                                       16, 0, 0);
    }
  };

  auto compute_store = [&](int i, int buf) {
    const int base = i * P_;
    float2 cf[ITERS];
    int ix[ITERS];
#pragma unroll
    for (int it = 0; it < ITERS; ++it) {
      const int s = it * (BLK / 16) + sbase;
      cf[it] = s_cf[base + s];
      ix[it] = s_ix[base + s] + f;
    }
    const int c = i * NBLOCKS + b;
    float4* __restrict__ gout = (float4*)(out_ + (size_t)c * (P_ * F_));
#pragma unroll
    for (int it = 0; it < ITERS; ++it) {
      const int s = it * (BLK / 16) + sbase;
      const float4 g00 = smap[buf][ix[it]];
      const float4 g01 = smap[buf][ix[it] + (F_ / 4)];            // x0+1
      const float4 g10 = smap[buf][ix[it] + W_ * (F_ / 4)];       // y0+1
      const float4 g11 = smap[buf][ix[it] + (W_ + 1) * (F_ / 4)]; // y0+1,x0+1

      const float wx1 = cf[it].x, wx0 = 1.0f - cf[it].x;
      const float wy1 = cf[it].y, wy0 = 1.0f - cf[it].y;

      f32x4 r;
      r.x = (g00.x * wx0 + g01.x * wx1) * wy0 + (g10.x * wx0 + g11.x * wx1) * wy1;
      r.y = (g00.y * wx0 + g01.y * wx1) * wy0 + (g10.y * wx0 + g11.y * wx1) * wy1;
      r.z = (g00.z * wx0 + g01.z * wx1) * wy0 + (g10.z * wx0 + g11.z * wx1) * wy1;
      r.w = (g00.w * wx0 + g01.w * wx1) * wy0 + (g10.w * wx0 + g11.w * wx1) * wy1;

      __builtin_nontemporal_store(r, (f32x4*)(gout + s * (F_ / 4) + f));
    }
  };

  // ---- prologue: stage complex 0; precompute ALL coefficients ----
  stage(b, 0);
#pragma unroll
  for (int g = tid; g < NC * P_; g += BLK) {   // 2 samples per thread
    const int i = g >> 8;                      // complex slot 0..7
    const int p = g & (P_ - 1);                // sample 0..255
    const int c = i * NBLOCKS + b;
    const float x = u_[(size_t)c * P_ + p] * (float)(W_ - 1);
    const float y = v_[(size_t)c * P_ + p] * (float)(H_ - 1);
    int x0 = (int)floorf(x);
    int y0 = (int)floorf(y);
    x0 = x0 < 0 ? 0 : (x0 > W_ - 2 ? W_ - 2 : x0);
    y0 = y0 < 0 ? 0 : (y0 > H_ - 2 ? H_ - 2 : y0);
    s_cf[g] = make_float2(x - (float)x0, y - (float)y0);
    s_ix[g] = (y0 * W_ + x0) * (F_ / 4);
  }
  __syncthreads();   // one-time full drain: DMA(0) landed, coeffs visible

  // ---- steady pipeline: loop body = exactly 4 DMA + 4 stores (vmem) ----
  int cur = 0;
  for (int i = 0; i < NC - 1; ++i) {
    const int nxt = cur ^ 1;

    stage((i + 1) * NBLOCKS + b, nxt);   // 4 global_load_lds (oldest vmem)
    __builtin_amdgcn_sched_barrier(0);   // DMAs stay above everything below

    compute_store(i, cur);               // ds_reads + VALU + 4 nt stores
    __builtin_amdgcn_sched_barrier(0);   // stores stay above the wait

    // vmcnt(4): everything except the 4 newest vmem ops (this phase's
    // stores) must complete -> prior stores + DMA(i+1) done, stores fly on.
    // lgkmcnt(0): all LDS reads of buf cur retired -> safe to re-DMA next
    // phase. Barrier publishes buffer swap to all 16 waves.
    asm volatile("s_waitcnt vmcnt(4) lgkmcnt(0)" ::: "memory");
    __builtin_amdgcn_s_barrier();
    __builtin_amdgcn_sched_barrier(0);   // nothing crosses the barrier

    cur = nxt;
  }
  compute_store(NC - 1, cur);            // final stores drain at endpgm
}

extern "C" void kernel_launch(void* const* d_in, const int* in_sizes, int n_in,
                              void* d_out, int out_size, void* d_ws, size_t ws_size,
                              hipStream_t stream) {
  const float* map_ = (const float*)d_in[0];
  const float* u_   = (const float*)d_in[1];
  const float* v_   = (const float*)d_in[2];
  float* out_ = (float*)d_out;

  ngf_fetch_kernel<<<NBLOCKS, BLK, 0, stream>>>(map_, u_, v_, out_);
}